// Round 15
// baseline (76.090 us; speedup 1.0000x reference)
//
#include <hip/hip_runtime.h>
#include <cstddef>

// SpectralPredictor via speculative segmentation (round-15).
// 200 bands x 576 segments of 64 px; each chain starts WUP=192 steps early
// with w = w0buf and discards warmup (clamped sign-LMS corner-collapse
// re-syncs exactly; WUP=768/384 both measured absmax==non-speculative 4.0).
// Segments need NOT be row-aligned: WUP/SEGPX/batch all multiples of 16 and
// row = 192 = 12 batches, so the x==0 border always lands on a batch
// boundary -> per-lane reset = 1 cmp + 2 cndmask PER BATCH. Mid-row starts
// only corrupt step-0 W/NW (absorbed by warmup like the w-init corruption).
// 115200 chains = 1800 waves (1.76/SIMD -> TLP hides load latency, which
// round-14 showed the compiler will not let us hide via prefetch depth).
// Masked path (p<0 zeros, row-0 N zeros) only for block 0 of each band;
// masks are batch-uniform per lane. g = med3(d*1e30, -.01, .01) as before.

#define Zb 200
#define Yd 192
#define Xd 192
#define WN 19
#define YX (Yd * Xd)
#define SEGPX 64
#define WUP 192
#define NB 16            // 256 steps = 16 batches of 16
#define TOUT 12          // batches >= 12 store output

typedef float f4 __attribute__((ext_vector_type(4)));

struct Quads { f4 c0,c1,c2,c3, n0,n1,n2,n3, s0,s1,s2,s3; };

template<bool MASKED>
__device__ __forceinline__ void loadq(Quads& q, const float* __restrict__ cb,
                                      const float* __restrict__ sb,
                                      int pc, float spm) {
  int pcc = pc, pn = pc - Xd;
  float mc = 1.f, mn = 1.f;
  if (MASKED) {
    mc = (pc >= 0) ? 1.f : 0.f;       // pre-band zeros (batch-uniform per lane)
    mn = (pc >= Xd) ? 1.f : 0.f;      // row-0 N zeros
    if (pcc < 0) pcc = 0;
    if (pn < 0) pn = 0;
  }
  q.c0 = *(const f4*)(cb + pcc);
  q.c1 = *(const f4*)(cb + pcc + 4);
  q.c2 = *(const f4*)(cb + pcc + 8);
  q.c3 = *(const f4*)(cb + pcc + 12);
  q.n0 = *(const f4*)(cb + pn);
  q.n1 = *(const f4*)(cb + pn + 4);
  q.n2 = *(const f4*)(cb + pn + 8);
  q.n3 = *(const f4*)(cb + pn + 12);
  const float ms = MASKED ? spm * mc : spm;
  q.s0 = *(const f4*)(sb + pcc) * ms;
  q.s1 = *(const f4*)(sb + pcc + 4) * ms;
  q.s2 = *(const f4*)(sb + pcc + 8) * ms;
  q.s3 = *(const f4*)(sb + pcc + 12) * ms;
  if (MASKED) {
    q.c0 *= mc; q.c1 *= mc; q.c2 *= mc; q.c3 *= mc;
    q.n0 *= mn; q.n1 *= mn; q.n2 *= mn; q.n3 *= mn;
  }
}

// one step: d's (forms identical to all passing rounds), g via med3 clamp,
// res via serial fma (matches prior rounds), pred clip, w update+clamp.
#define ST1(CU, NN, SPV, PD, RD) {                                            \
    const float d1 = (NN) - Wv;                                               \
    const float d2 = Wv - NWv;                                                \
    const float d3 = NWv - (NN);                                              \
    const float d4 = __builtin_fmaf(-2.f, NWv, (NN) + Wv);                    \
    const float g1 = __builtin_amdgcn_fmed3f(d1 * BIG, gn, gp);               \
    const float g2 = __builtin_amdgcn_fmed3f(d2 * BIG, gn, gp);               \
    const float g3 = __builtin_amdgcn_fmed3f(d3 * BIG, gn, gp);               \
    const float g4 = __builtin_amdgcn_fmed3f(d4 * BIG, gn, gp);               \
    const float res = __builtin_fmaf(-w3, (SPV), __builtin_fmaf(-w2, NWv,     \
                      __builtin_fmaf(-w1, Wv, __builtin_fmaf(-w0, (NN), (CU))))); \
    PD = __builtin_amdgcn_fmed3f((CU) - res, -32768.f, 32767.f);              \
    RD = res;                                                                 \
    w0 = __builtin_amdgcn_fmed3f(__builtin_fmaf(res, g1, w0), -1.f, 1.f);     \
    w1 = __builtin_amdgcn_fmed3f(__builtin_fmaf(res, g2, w1), -1.f, 1.f);     \
    w2 = __builtin_amdgcn_fmed3f(__builtin_fmaf(res, g3, w2), -1.f, 1.f);     \
    w3 = __builtin_amdgcn_fmed3f(__builtin_fmaf(res, g4, w3), -1.f, 1.f);     \
    Wv = (CU); NWv = (NN); }

// consume QC_, prefetch batch T+1 into QN_ (double buffer); per-lane
// x-phase register xr = x-coordinate of this batch's first pixel (mod 192);
// xr == 0 <=> row start -> W/NW reset (always batch-aligned, see header).
#define DOBATCH(QC_, QN_, T) {                                                \
    if ((T) + 1 < NB) loadq<MASKED>(QN_, cb, sb, p0 + ((T) + 1) * 16, spm);   \
    float Wv  = (xr == 0) ? 0.f : pCu;                                        \
    float NWv = (xr == 0) ? 0.f : pN;                                         \
    f4 P0, P1, P2, P3, R0, R1, R2, R3;                                        \
    ST1(QC_.c0.x, QC_.n0.x, QC_.s0.x, P0.x, R0.x)                             \
    ST1(QC_.c0.y, QC_.n0.y, QC_.s0.y, P0.y, R0.y)                             \
    ST1(QC_.c0.z, QC_.n0.z, QC_.s0.z, P0.z, R0.z)                             \
    ST1(QC_.c0.w, QC_.n0.w, QC_.s0.w, P0.w, R0.w)                             \
    ST1(QC_.c1.x, QC_.n1.x, QC_.s1.x, P1.x, R1.x)                             \
    ST1(QC_.c1.y, QC_.n1.y, QC_.s1.y, P1.y, R1.y)                             \
    ST1(QC_.c1.z, QC_.n1.z, QC_.s1.z, P1.z, R1.z)                             \
    ST1(QC_.c1.w, QC_.n1.w, QC_.s1.w, P1.w, R1.w)                             \
    ST1(QC_.c2.x, QC_.n2.x, QC_.s2.x, P2.x, R2.x)                             \
    ST1(QC_.c2.y, QC_.n2.y, QC_.s2.y, P2.y, R2.y)                             \
    ST1(QC_.c2.z, QC_.n2.z, QC_.s2.z, P2.z, R2.z)                             \
    ST1(QC_.c2.w, QC_.n2.w, QC_.s2.w, P2.w, R2.w)                             \
    ST1(QC_.c3.x, QC_.n3.x, QC_.s3.x, P3.x, R3.x)                             \
    ST1(QC_.c3.y, QC_.n3.y, QC_.s3.y, P3.y, R3.y)                             \
    ST1(QC_.c3.z, QC_.n3.z, QC_.s3.z, P3.z, R3.z)                             \
    ST1(QC_.c3.w, QC_.n3.w, QC_.s3.w, P3.w, R3.w)                             \
    pCu = QC_.c3.w; pN = QC_.n3.w;                                            \
    xr = (xr == Xd - 16) ? 0 : xr + 16;                                       \
    if ((T) >= TOUT) {                                                        \
      const int pc = p0 + (T) * 16;                                           \
      f4* pp = (f4*)(opred + pc);                                             \
      f4* rr = (f4*)(ores + pc);                                              \
      pp[0] = P0; pp[1] = P1; pp[2] = P2; pp[3] = P3;                         \
      rr[0] = R0; rr[1] = R1; rr[2] = R2; rr[3] = R3;                         \
    } }

template<bool MASKED>
__device__ __forceinline__ void runchain(const float* __restrict__ cb,
                                         const float* __restrict__ sb,
                                         float spm, int p0,
                                         float w0, float w1, float w2, float w3,
                                         float* __restrict__ opred,
                                         float* __restrict__ ores) {
  const float BIG = 1e30f, gn = -0.01f, gp = 0.01f;
  float pCu = 0.f, pN = 0.f;
  int xr = ((p0 % Xd) + Xd) % Xd;        // x of first batch's first pixel
  Quads QA, QB;
  loadq<MASKED>(QA, cb, sb, p0, spm);
#pragma unroll 1
  for (int t = 0; t < NB; t += 2) {
    DOBATCH(QA, QB, t)
    DOBATCH(QB, QA, t + 1)
  }
}

__global__ __launch_bounds__(64, 1)
void spectral_predict(const float* __restrict__ img,
                      const float* __restrict__ w0buf,
                      float* __restrict__ outp) {
  const int bid  = blockIdx.x;
  const int band = bid / 9;             // 9 blocks (576 segs) per band
  const int bl   = bid % 9;
  const int seg  = bl * 64 + threadIdx.x;
  const int p0   = seg * SEGPX - WUP;

  const float* cb = img + (size_t)band * YX;
  const int zp = (band - 15 > 0) ? band - 15 : 0;
  const float* sb = img + (size_t)zp * YX;
  const float spm = (band > 0) ? 1.f : 0.f;

  const float w0 = w0buf[band * WN + 0];
  const float w1 = w0buf[band * WN + 1];
  const float w2 = w0buf[band * WN + 2];
  const float w3 = w0buf[band * WN + 3];

  float* opred = outp + (size_t)band * YX;
  float* ores  = opred + (size_t)Zb * YX;

  if (bl == 0) runchain<true >(cb, sb, spm, p0, w0, w1, w2, w3, opred, ores);
  else         runchain<false>(cb, sb, spm, p0, w0, w1, w2, w3, opred, ores);
}

extern "C" void kernel_launch(void* const* d_in, const int* in_sizes, int n_in,
                              void* d_out, int out_size, void* d_ws, size_t ws_size,
                              hipStream_t stream) {
  const float* img = (const float*)d_in[0];
  const float* w0  = (const float*)d_in[1];
  float* out = (float*)d_out;
  hipLaunchKernelGGL(spectral_predict, dim3(1800), dim3(64), 0, stream,
                     img, w0, out);
}